// Round 12
// baseline (790.966 us; speedup 1.0000x reference)
//
#include <hip/hip_runtime.h>
#include <hip/hip_bf16.h>
#include <math.h>

#define IGNORE_INDEX (-100)

static constexpr int Dc = 1024, Vc = 128000;
static constexpr int Mrows = 2048;        // B*S
static constexpr int Kdim = 1024;
static constexpr int NT = Kdim / 64;      // 16 K-tiles of BK=64
static constexpr int NCHUNK = Vc / 64;    // 2000 partial chunks per row

typedef __bf16 bf16x8_t __attribute__((ext_vector_type(8)));
typedef float f32x4_t __attribute__((ext_vector_type(4)));

__device__ __forceinline__ ushort f2bf(float f) {
  union { float f; unsigned u; } v; v.f = f;
  unsigned u = v.u;
  unsigned r = (u + 0x7FFFu + ((u >> 16) & 1u)) >> 16;  // round-nearest-even
  return (ushort)r;
}

// ---------------- cast fp32 -> bf16 (vectorized, grid-stride) ----------------
__global__ void cast_f32_bf16(const float* __restrict__ in, ushort* __restrict__ out,
                              size_t n4) {
  size_t i = (size_t)blockIdx.x * blockDim.x + threadIdx.x;
  size_t stride = (size_t)gridDim.x * blockDim.x;
  for (; i < n4; i += stride) {
    float4 v = reinterpret_cast<const float4*>(in)[i];
    ushort4 o;
    o.x = f2bf(v.x); o.y = f2bf(v.y); o.z = f2bf(v.z); o.w = f2bf(v.w);
    reinterpret_cast<ushort4*>(out)[i] = o;
  }
}

// ---------------- target logits: fp32 dot(hidden[r], weight[t[r]]) ----------------
__global__ void tgt_kernel(const float* __restrict__ hidden, const float* __restrict__ weight,
                           const int* __restrict__ targets, float* __restrict__ tgt) {
  int row = blockIdx.x * 4 + (threadIdx.x >> 6);
  int lane = threadIdx.x & 63;
  if (row >= Mrows) return;
  int t = targets[row];
  float sum = 0.f;
  if (t != IGNORE_INDEX) {
    const float* h = hidden + (size_t)row * Kdim;
    const float* wv = weight + (size_t)t * Kdim;
    for (int k = lane * 4; k < Kdim; k += 64 * 4) {
      float4 a = *reinterpret_cast<const float4*>(h + k);
      float4 b = *reinterpret_cast<const float4*>(wv + k);
      sum += a.x * b.x + a.y * b.y + a.z * b.z + a.w * b.w;
    }
  }
  #pragma unroll
  for (int d = 1; d < 64; d <<= 1) sum += __shfl_xor(sum, d);
  if (lane == 0) tgt[row] = sum;
}

// ------- 256x256 8-wave SOFTWARE-PIPELINED quadrant GEMM + fused partial LSE --
// Geometry/addressing/swizzle identical to R10 (verified: PASS, 0 conflicts):
// LDS 2 dbuf x {A0,A1,B0,B1} regions of [128 rows][64 k], 128B rows,
// slot' = slot ^ (row&7); linear LDS dest + inverse-swizzled global source +
// swizzled ds_read; kk=1 frag at offset ^64 (XOR, not +64).
// NEW (R11 lesson): ds_reads issued ONE PHASE BEFORE their consuming MFMA so
// the 8-wave LDS read burst drains under the previous phase's MFMA:
//   ph1: read SB1(t)   | stage half1(t+1) | MFMA Q00(aC,bL) | barrier
//   ph2: read SA1(t)   | stage half2(t+1) | MFMA Q01(aC,bH) | barrier
//   ph3:                                    MFMA Q10(aN,bL) | barrier
//   ph4: vmcnt(0)+barrier; read SA0/SB0(t+1) from other buf | MFMA Q11(aN,bH)
// vmcnt(0) is UNIFORM (R8 lesson: block-cooperative staging forbids per-wave
// counted waits at a boundary other waves read after).
__device__ __forceinline__ void stage_region(ushort* region, const ushort* gpanel,
                                             int rowBase, int k0, int tid) {
  #pragma unroll
  for (int ld = 0; ld < 2; ++ld) {
    int c = ld * 512 + tid;            // 16B chunk id 0..1023 (8 chunks/128B row)
    int r = c >> 3, slot = c & 7;
    int ko = ((slot ^ (r & 7)) << 3);  // inverse-swizzled source k-offset (elems)
    const ushort* g = gpanel + (size_t)(rowBase + r) * Kdim + k0 + ko;
    __builtin_amdgcn_global_load_lds(
        (const __attribute__((address_space(1))) void*)g,
        (__attribute__((address_space(3))) void*)(region + c * 8), 16, 0, 0);
  }
}

#define MFMA_BF16(A, B, C) __builtin_amdgcn_mfma_f32_16x16x32_bf16((A), (B), (C), 0, 0, 0)

__global__ __launch_bounds__(512, 2) void gemm_lse8(const ushort* __restrict__ Abf,
                                                    const ushort* __restrict__ Bbf,
                                                    float2* __restrict__ part) {
  __shared__ ushort lds[2][4][8192];   // [dbuf][A0,A1,B0,B1][128*64] = 128KB
  const int tid = threadIdx.x;
  const int wid = tid >> 6, lane = tid & 63;
  const int wr = wid >> 2, wc = wid & 3;        // 2M x 4N wave grid
  const int l15 = lane & 15, l16 = lane >> 4;
  const int bid = blockIdx.x;
  const int mb = bid & 7;              // bid%8 = XCD -> each XCD owns one A panel
  const int nb = bid >> 3;             // 0..499; all XCDs stream same B panel

  const int koff0 = ((l16 ^ (l15 & 7)) << 4);      // bytes
  const int aBase = l15 * 128 + koff0;             // + mi*2048 per frag
  const int bBase = ((wc & 1) * 64 + l15) * 128 + koff0;  // + ni*2048 per frag

  const ushort* gA = Abf + (size_t)(mb * 256) * Kdim;
  const ushort* gB = Bbf + (size_t)(nb * 256) * Kdim;

  f32x4_t acc[8][4];
  #pragma unroll
  for (int i = 0; i < 8; ++i)
    #pragma unroll
    for (int j = 0; j < 4; ++j)
      acc[i][j] = (f32x4_t){0.f, 0.f, 0.f, 0.f};

  bf16x8_t aC[8], aN[8], bL[4], bH[4];

  // prologue: stage tile 0, drain, then preload SA0/SB0 of tile 0
  stage_region(lds[0][0], gA, 0, 0, tid);
  stage_region(lds[0][2], gB, 0, 0, tid);
  stage_region(lds[0][1], gA, 128, 0, tid);
  stage_region(lds[0][3], gB, 128, 0, tid);
  asm volatile("s_waitcnt vmcnt(0)" ::: "memory");
  __builtin_amdgcn_s_barrier();
  {
    const char* Ar = (const char*)lds[0][wr];
    const char* Br = (const char*)lds[0][2 + (wc >> 1)];
    #pragma unroll
    for (int mi = 0; mi < 4; ++mi) {
      const int aOff = aBase + mi * 2048;
      aC[mi * 2 + 0] = *reinterpret_cast<const bf16x8_t*>(Ar + aOff);
      aC[mi * 2 + 1] = *reinterpret_cast<const bf16x8_t*>(Ar + (aOff ^ 64));
    }
    #pragma unroll
    for (int ni = 0; ni < 2; ++ni) {
      const int bOff = bBase + ni * 2048;
      bL[ni * 2 + 0] = *reinterpret_cast<const bf16x8_t*>(Br + bOff);
      bL[ni * 2 + 1] = *reinterpret_cast<const bf16x8_t*>(Br + (bOff ^ 64));
    }
  }

  for (int t = 0; t < NT; ++t) {
    const int buf = t & 1, nbf = buf ^ 1;
    const char* Ar = (const char*)lds[buf][wr];
    const char* Br = (const char*)lds[buf][2 + (wc >> 1)];
    const bool more = (t + 1 < NT);
    const int k1 = (t + 1) * 64;

    // ---- ph1: read SB1(t); stage half1(t+1); MFMA Q00(aC,bL) ----
    #pragma unroll
    for (int ni = 2; ni < 4; ++ni) {
      const int bOff = bBase + ni * 2048;
      bH[(ni - 2) * 2 + 0] = *reinterpret_cast<const bf16x8_t*>(Br + bOff);
      bH[(ni - 2) * 2 + 1] = *reinterpret_cast<const bf16x8_t*>(Br + (bOff ^ 64));
    }
    if (more) {
      stage_region(lds[nbf][0], gA, 0, k1, tid);
      stage_region(lds[nbf][2], gB, 0, k1, tid);
    }
    __builtin_amdgcn_s_setprio(1);
    #pragma unroll
    for (int mi = 0; mi < 4; ++mi) {
      acc[mi][0] = MFMA_BF16(aC[mi * 2 + 0], bL[0], acc[mi][0]);
      acc[mi][0] = MFMA_BF16(aC[mi * 2 + 1], bL[1], acc[mi][0]);
      acc[mi][1] = MFMA_BF16(aC[mi * 2 + 0], bL[2], acc[mi][1]);
      acc[mi][1] = MFMA_BF16(aC[mi * 2 + 1], bL[3], acc[mi][1]);
    }
    __builtin_amdgcn_s_setprio(0);
    __builtin_amdgcn_s_barrier();

    // ---- ph2: read SA1(t); stage half2(t+1); MFMA Q01(aC,bH) ----
    #pragma unroll
    for (int mi = 4; mi < 8; ++mi) {
      const int aOff = aBase + mi * 2048;
      aN[(mi - 4) * 2 + 0] = *reinterpret_cast<const bf16x8_t*>(Ar + aOff);
      aN[(mi - 4) * 2 + 1] = *reinterpret_cast<const bf16x8_t*>(Ar + (aOff ^ 64));
    }
    if (more) {
      stage_region(lds[nbf][1], gA, 128, k1, tid);
      stage_region(lds[nbf][3], gB, 128, k1, tid);
    }
    __builtin_amdgcn_s_setprio(1);
    #pragma unroll
    for (int mi = 0; mi < 4; ++mi) {
      acc[mi][2] = MFMA_BF16(aC[mi * 2 + 0], bH[0], acc[mi][2]);
      acc[mi][2] = MFMA_BF16(aC[mi * 2 + 1], bH[1], acc[mi][2]);
      acc[mi][3] = MFMA_BF16(aC[mi * 2 + 0], bH[2], acc[mi][3]);
      acc[mi][3] = MFMA_BF16(aC[mi * 2 + 1], bH[3], acc[mi][3]);
    }
    __builtin_amdgcn_s_setprio(0);
    __builtin_amdgcn_s_barrier();

    // ---- ph3: MFMA Q10(aN,bL) ----
    __builtin_amdgcn_s_setprio(1);
    #pragma unroll
    for (int mi = 0; mi < 4; ++mi) {
      acc[mi + 4][0] = MFMA_BF16(aN[mi * 2 + 0], bL[0], acc[mi + 4][0]);
      acc[mi + 4][0] = MFMA_BF16(aN[mi * 2 + 1], bL[1], acc[mi + 4][0]);
      acc[mi + 4][1] = MFMA_BF16(aN[mi * 2 + 0], bL[2], acc[mi + 4][1]);
      acc[mi + 4][1] = MFMA_BF16(aN[mi * 2 + 1], bL[3], acc[mi + 4][1]);
    }
    __builtin_amdgcn_s_setprio(0);
    __builtin_amdgcn_s_barrier();

    // ---- ph4: drain+sync, read SA0/SB0(t+1) from other buf; MFMA Q11(aN,bH) ----
    if (more) {
      asm volatile("s_waitcnt vmcnt(0)" ::: "memory");
      __builtin_amdgcn_s_barrier();
      const char* Ar2 = (const char*)lds[nbf][wr];
      const char* Br2 = (const char*)lds[nbf][2 + (wc >> 1)];
      #pragma unroll
      for (int mi = 0; mi < 4; ++mi) {
        const int aOff = aBase + mi * 2048;
        aC[mi * 2 + 0] = *reinterpret_cast<const bf16x8_t*>(Ar2 + aOff);
        aC[mi * 2 + 1] = *reinterpret_cast<const bf16x8_t*>(Ar2 + (aOff ^ 64));
      }
      #pragma unroll
      for (int ni = 0; ni < 2; ++ni) {
        const int bOff = bBase + ni * 2048;
        bL[ni * 2 + 0] = *reinterpret_cast<const bf16x8_t*>(Br2 + bOff);
        bL[ni * 2 + 1] = *reinterpret_cast<const bf16x8_t*>(Br2 + (bOff ^ 64));
      }
    }
    __builtin_amdgcn_s_setprio(1);
    #pragma unroll
    for (int mi = 0; mi < 4; ++mi) {
      acc[mi + 4][2] = MFMA_BF16(aN[mi * 2 + 0], bH[0], acc[mi + 4][2]);
      acc[mi + 4][2] = MFMA_BF16(aN[mi * 2 + 1], bH[1], acc[mi + 4][2]);
      acc[mi + 4][3] = MFMA_BF16(aN[mi * 2 + 0], bH[2], acc[mi + 4][3]);
      acc[mi + 4][3] = MFMA_BF16(aN[mi * 2 + 1], bH[3], acc[mi + 4][3]);
    }
    __builtin_amdgcn_s_setprio(0);
  }

  // fused partial-LSE epilogue. acc[mi][ni][j]: row = wr*128+mi*16+l16*4+j,
  // col = wc*64+ni*16+l15 (m89-verified C/D layout)
  const int chunk = nb * 4 + wc;
  #pragma unroll
  for (int mi = 0; mi < 8; ++mi) {
    #pragma unroll
    for (int j = 0; j < 4; ++j) {
      float v0 = acc[mi][0][j], v1 = acc[mi][1][j], v2 = acc[mi][2][j], v3 = acc[mi][3][j];
      float mloc = fmaxf(fmaxf(v0, v1), fmaxf(v2, v3));
      #pragma unroll
      for (int d = 1; d < 16; d <<= 1) mloc = fmaxf(mloc, __shfl_xor(mloc, d));
      float sloc = __expf(v0 - mloc) + __expf(v1 - mloc) +
                   __expf(v2 - mloc) + __expf(v3 - mloc);
      #pragma unroll
      for (int d = 1; d < 16; d <<= 1) sloc += __shfl_xor(sloc, d);
      if (l15 == 0) {
        int grow = mb * 256 + wr * 128 + mi * 16 + l16 * 4 + j;
        part[(size_t)grow * NCHUNK + chunk] = make_float2(mloc, sloc);
      }
    }
  }
}

// ---------------- per-row merge of partials -> nll[row] ----------------
__device__ __forceinline__ void merge_ms(float& m, float& s, float m2, float s2) {
  if (m2 > m) { s = s * __expf(m - m2) + s2; m = m2; }
  else        { s += s2 * __expf(m2 - m); }
}

__global__ void lse_reduce(const float2* __restrict__ part, const float* __restrict__ tgt,
                           const int* __restrict__ targets, float* __restrict__ nll) {
  int row = blockIdx.x;
  const float2* p = part + (size_t)row * NCHUNK;
  float m = -INFINITY, s = 0.f;
  for (int c = threadIdx.x; c < NCHUNK; c += blockDim.x) {
    float2 v = p[c];
    merge_ms(m, s, v.x, v.y);
  }
  #pragma unroll
  for (int d = 1; d < 64; d <<= 1) {
    float m2 = __shfl_xor(m, d), s2 = __shfl_xor(s, d);
    merge_ms(m, s, m2, s2);
  }
  __shared__ float sm[4], ss[4];
  int wid = threadIdx.x >> 6, lane = threadIdx.x & 63;
  if (lane == 0) { sm[wid] = m; ss[wid] = s; }
  __syncthreads();
  if (threadIdx.x == 0) {
    #pragma unroll
    for (int w2 = 1; w2 < 4; ++w2) merge_ms(m, s, sm[w2], ss[w2]);
    int t = targets[row];
    float out = 0.f;
    if (t != IGNORE_INDEX) out = m + logf(s) - tgt[row];
    nll[row] = out;
  }
}

// ---------------- final scalar: sum(nll)/count ----------------
__global__ void final_kernel(const float* __restrict__ nll, const int* __restrict__ targets,
                             float* __restrict__ out) {
  float sum = 0.f, cnt = 0.f;
  for (int i = threadIdx.x; i < Mrows; i += 64) {
    sum += nll[i];
    cnt += (targets[i] != IGNORE_INDEX) ? 1.f : 0.f;
  }
  #pragma unroll
  for (int d = 1; d < 64; d <<= 1) {
    sum += __shfl_xor(sum, d);
    cnt += __shfl_xor(cnt, d);
  }
  if (threadIdx.x == 0)
    out[0] = (cnt == 0.f) ? sum : sum / fmaxf(cnt, 1.f);
}

extern "C" void kernel_launch(void* const* d_in, const int* in_sizes, int n_in,
                              void* d_out, int out_size, void* d_ws, size_t ws_size,
                              hipStream_t stream) {
  const float* hidden = (const float*)d_in[0];   // [2,1024,1024] f32
  const float* weight = (const float*)d_in[1];   // [128000,1024] f32
  const int* targets  = (const int*)d_in[2];     // [2,1024] i32
  float* out = (float*)d_out;

  char* ws = (char*)d_ws;
  size_t off = 0;
  ushort* wbf = (ushort*)(ws + off); off += (size_t)Vc * Dc * sizeof(ushort);
  ushort* hbf = (ushort*)(ws + off); off += (size_t)Mrows * Dc * sizeof(ushort);
  float2* part = (float2*)(ws + off); off += (size_t)Mrows * NCHUNK * sizeof(float2);
  float* tgt = (float*)(ws + off); off += Mrows * sizeof(float);
  float* nll = (float*)(ws + off); off += Mrows * sizeof(float);
  (void)ws_size; (void)in_sizes; (void)n_in; (void)out_size;

  cast_f32_bf16<<<2048, 256, 0, stream>>>(weight, wbf, (size_t)Vc * Dc / 4);
  cast_f32_bf16<<<256, 256, 0, stream>>>(hidden, hbf, (size_t)Mrows * Dc / 4);
  tgt_kernel<<<Mrows / 4, 256, 0, stream>>>(hidden, weight, targets, tgt);

  gemm_lse8<<<4000, 512, 0, stream>>>(hbf, wbf, part);  // mb=bid&7 (XCD), nb=bid>>3

  lse_reduce<<<Mrows, 256, 0, stream>>>(part, tgt, targets, nll);
  final_kernel<<<1, 64, 0, stream>>>(nll, targets, out);
}

// Round 13
// 752.742 us; speedup vs baseline: 1.0508x; 1.0508x over previous
//
#include <hip/hip_runtime.h>
#include <hip/hip_bf16.h>
#include <math.h>

#define IGNORE_INDEX (-100)

static constexpr int Dc = 1024, Vc = 128000;
static constexpr int Mrows = 2048;        // B*S
static constexpr int Kdim = 1024;
static constexpr int BK = 32;
static constexpr int NT = Kdim / BK;      // 32 K-tiles
static constexpr int NCHUNK = Vc / 64;    // 2000 partial chunks per row

typedef __bf16 bf16x8_t __attribute__((ext_vector_type(8)));
typedef float f32x4_t __attribute__((ext_vector_type(4)));

__device__ __forceinline__ ushort f2bf(float f) {
  union { float f; unsigned u; } v; v.f = f;
  unsigned u = v.u;
  unsigned r = (u + 0x7FFFu + ((u >> 16) & 1u)) >> 16;  // round-nearest-even
  return (ushort)r;
}

// ---------------- cast fp32 -> bf16 (vectorized, grid-stride) ----------------
__global__ void cast_f32_bf16(const float* __restrict__ in, ushort* __restrict__ out,
                              size_t n4) {
  size_t i = (size_t)blockIdx.x * blockDim.x + threadIdx.x;
  size_t stride = (size_t)gridDim.x * blockDim.x;
  for (; i < n4; i += stride) {
    float4 v = reinterpret_cast<const float4*>(in)[i];
    ushort4 o;
    o.x = f2bf(v.x); o.y = f2bf(v.y); o.z = f2bf(v.z); o.w = f2bf(v.w);
    reinterpret_cast<ushort4*>(out)[i] = o;
  }
}

// ---------------- target logits: fp32 dot(hidden[r], weight[t[r]]) ----------------
__global__ void tgt_kernel(const float* __restrict__ hidden, const float* __restrict__ weight,
                           const int* __restrict__ targets, float* __restrict__ tgt) {
  int row = blockIdx.x * 4 + (threadIdx.x >> 6);
  int lane = threadIdx.x & 63;
  if (row >= Mrows) return;
  int t = targets[row];
  float sum = 0.f;
  if (t != IGNORE_INDEX) {
    const float* h = hidden + (size_t)row * Kdim;
    const float* wv = weight + (size_t)t * Kdim;
    for (int k = lane * 4; k < Kdim; k += 64 * 4) {
      float4 a = *reinterpret_cast<const float4*>(h + k);
      float4 b = *reinterpret_cast<const float4*>(wv + k);
      sum += a.x * b.x + a.y * b.y + a.z * b.z + a.w * b.w;
    }
  }
  #pragma unroll
  for (int d = 1; d < 64; d <<= 1) sum += __shfl_xor(sum, d);
  if (lane == 0) tgt[row] = sum;
}

// ------ 128x256 8-wave 2-BLOCK/CU GEMM (bf16 MFMA) + fused partial LSE --------
// R12 lesson: three intra-block schedules all hit ~660us / 35% MfmaUtil at
// 1 block/CU (acc 128 AGPR + ~128 VGPR = full unified file; 128KB LDS). The
// missing mechanism is CROSS-BLOCK overlap (m114): co-resident independent
// blocks hide each other's barrier/drain stalls. This kernel halves both
// footprints: per-wave output 64x64 (acc=64), BK=32 dbuf LDS=48KB ->
// 2 blocks/CU, 16 waves/CU. Schedule is the SIMPLE 1-barrier-per-tile loop.
// Swizzle (R10-measured ZERO conflicts, 64B rows): 16B slot' = slot^((row>>1)&3),
// linear LDS dest + inverse-swizzled GLOBAL source + swizzled ds_read (rule #21).
#define MFMA_BF16(A, B, C) __builtin_amdgcn_mfma_f32_16x16x32_bf16((A), (B), (C), 0, 0, 0)
#define GLDS(g, l) __builtin_amdgcn_global_load_lds( \
    (const __attribute__((address_space(1))) void*)(g), \
    (__attribute__((address_space(3))) void*)(l), 16, 0, 0)

__global__ __launch_bounds__(512, 4) void gemm_lse2b(const ushort* __restrict__ Abf,
                                                     const ushort* __restrict__ Bbf,
                                                     float2* __restrict__ part) {
  __shared__ ushort lds[2][3 * 4096];  // [dbuf][A(128x32)=4K elems | B(256x32)=8K elems]
  const int tid = threadIdx.x;
  const int wid = tid >> 6, lane = tid & 63;
  const int wr = wid >> 2, wc = wid & 3;        // 2M x 4N wave grid, wave = 64x64 out
  const int l15 = lane & 15, l16 = lane >> 4;
  const int bid = blockIdx.x;
  const int mb = bid & 15;             // 16 M-blocks share one B panel (cross-XCD)
  const int nb = bid >> 4;             // 0..499

  // staging: A chunk c=tid (r=c>>2 in 0..127); B chunks c=tid, tid+512 (r 0..255)
  const int sr = tid >> 2, sslot = tid & 3;
  const int sko = ((sslot ^ ((sr >> 1) & 3)) << 3);       // inverse-swizzled src k
  const int sr2 = (tid + 512) >> 2;
  const int sko2 = ((sslot ^ ((sr2 >> 1) & 3)) << 3);
  const ushort* gA = Abf + (size_t)(mb * 128) * Kdim;
  const ushort* gB = Bbf + (size_t)(nb * 256) * Kdim;
  const ushort* sgA = gA + (size_t)sr * Kdim + sko;
  const ushort* sgB0 = gB + (size_t)sr * Kdim + sko;
  const ushort* sgB1 = gB + (size_t)sr2 * Kdim + sko2;

  // read-side: row stride 64B; frag row bases are multiples of 16 ->
  // (row>>1)&3 = (l15>>1)&3; logical k-slot l16 lives at slot l16^((l15>>1)&3).
  const int koff = ((l16 ^ ((l15 >> 1) & 3)) << 4);       // bytes
  const int aBase = (wr * 64 + l15) * 64 + koff;          // + mi*1024
  const int bBase = (wc * 64 + l15) * 64 + koff;          // + ni*1024 (within B)

  f32x4_t acc[4][4];
  #pragma unroll
  for (int i = 0; i < 4; ++i)
    #pragma unroll
    for (int j = 0; j < 4; ++j)
      acc[i][j] = (f32x4_t){0.f, 0.f, 0.f, 0.f};

  #define STAGE(bufp, k0) do { \
    GLDS(sgA + (k0), bufp + tid * 8); \
    GLDS(sgB0 + (k0), bufp + 4096 + tid * 8); \
    GLDS(sgB1 + (k0), bufp + 4096 + 4096 + tid * 8); \
  } while (0)

  STAGE(lds[0], 0);
  asm volatile("s_waitcnt vmcnt(0)" ::: "memory");
  __builtin_amdgcn_s_barrier();

  for (int t = 0; t < NT; ++t) {
    const int buf = t & 1;
    if (t + 1 < NT) STAGE(lds[buf ^ 1], (t + 1) * BK);
    const char* Ar = (const char*)lds[buf];
    const char* Br = (const char*)lds[buf] + 8192;
    bf16x8_t a[4], b[4];
    #pragma unroll
    for (int mi = 0; mi < 4; ++mi)
      a[mi] = *reinterpret_cast<const bf16x8_t*>(Ar + aBase + mi * 1024);
    #pragma unroll
    for (int ni = 0; ni < 4; ++ni)
      b[ni] = *reinterpret_cast<const bf16x8_t*>(Br + bBase + ni * 1024);
    __builtin_amdgcn_s_setprio(1);
    #pragma unroll
    for (int mi = 0; mi < 4; ++mi)
      #pragma unroll
      for (int ni = 0; ni < 4; ++ni)
        acc[mi][ni] = MFMA_BF16(a[mi], b[ni], acc[mi][ni]);
    __builtin_amdgcn_s_setprio(0);
    if (t + 1 < NT) {
      asm volatile("s_waitcnt vmcnt(0)" ::: "memory");
      __builtin_amdgcn_s_barrier();
    }
  }
  #undef STAGE

  // fused partial-LSE epilogue. acc[mi][ni][j]: row = wr*64+mi*16+l16*4+j,
  // col = wc*64+ni*16+l15 (m89-verified C/D layout)
  const int chunk = nb * 4 + wc;
  #pragma unroll
  for (int mi = 0; mi < 4; ++mi) {
    #pragma unroll
    for (int j = 0; j < 4; ++j) {
      float v0 = acc[mi][0][j], v1 = acc[mi][1][j], v2 = acc[mi][2][j], v3 = acc[mi][3][j];
      float mloc = fmaxf(fmaxf(v0, v1), fmaxf(v2, v3));
      #pragma unroll
      for (int d = 1; d < 16; d <<= 1) mloc = fmaxf(mloc, __shfl_xor(mloc, d));
      float sloc = __expf(v0 - mloc) + __expf(v1 - mloc) +
                   __expf(v2 - mloc) + __expf(v3 - mloc);
      #pragma unroll
      for (int d = 1; d < 16; d <<= 1) sloc += __shfl_xor(sloc, d);
      if (l15 == 0) {
        int grow = mb * 128 + wr * 64 + mi * 16 + l16 * 4 + j;
        part[(size_t)grow * NCHUNK + chunk] = make_float2(mloc, sloc);
      }
    }
  }
}

// ---------------- per-row merge of partials -> nll[row] ----------------
__device__ __forceinline__ void merge_ms(float& m, float& s, float m2, float s2) {
  if (m2 > m) { s = s * __expf(m - m2) + s2; m = m2; }
  else        { s += s2 * __expf(m2 - m); }
}

__global__ void lse_reduce(const float2* __restrict__ part, const float* __restrict__ tgt,
                           const int* __restrict__ targets, float* __restrict__ nll) {
  int row = blockIdx.x;
  const float2* p = part + (size_t)row * NCHUNK;
  float m = -INFINITY, s = 0.f;
  for (int c = threadIdx.x; c < NCHUNK; c += blockDim.x) {
    float2 v = p[c];
    merge_ms(m, s, v.x, v.y);
  }
  #pragma unroll
  for (int d = 1; d < 64; d <<= 1) {
    float m2 = __shfl_xor(m, d), s2 = __shfl_xor(s, d);
    merge_ms(m, s, m2, s2);
  }
  __shared__ float sm[4], ss[4];
  int wid = threadIdx.x >> 6, lane = threadIdx.x & 63;
  if (lane == 0) { sm[wid] = m; ss[wid] = s; }
  __syncthreads();
  if (threadIdx.x == 0) {
    #pragma unroll
    for (int w2 = 1; w2 < 4; ++w2) merge_ms(m, s, sm[w2], ss[w2]);
    int t = targets[row];
    float out = 0.f;
    if (t != IGNORE_INDEX) out = m + logf(s) - tgt[row];
    nll[row] = out;
  }
}

// ---------------- final scalar: sum(nll)/count ----------------
__global__ void final_kernel(const float* __restrict__ nll, const int* __restrict__ targets,
                             float* __restrict__ out) {
  float sum = 0.f, cnt = 0.f;
  for (int i = threadIdx.x; i < Mrows; i += 64) {
    sum += nll[i];
    cnt += (targets[i] != IGNORE_INDEX) ? 1.f : 0.f;
  }
  #pragma unroll
  for (int d = 1; d < 64; d <<= 1) {
    sum += __shfl_xor(sum, d);
    cnt += __shfl_xor(cnt, d);
  }
  if (threadIdx.x == 0)
    out[0] = (cnt == 0.f) ? sum : sum / fmaxf(cnt, 1.f);
}

extern "C" void kernel_launch(void* const* d_in, const int* in_sizes, int n_in,
                              void* d_out, int out_size, void* d_ws, size_t ws_size,
                              hipStream_t stream) {
  const float* hidden = (const float*)d_in[0];   // [2,1024,1024] f32
  const float* weight = (const float*)d_in[1];   // [128000,1024] f32
  const int* targets  = (const int*)d_in[2];     // [2,1024] i32
  float* out = (float*)d_out;

  char* ws = (char*)d_ws;
  size_t off = 0;
  ushort* wbf = (ushort*)(ws + off); off += (size_t)Vc * Dc * sizeof(ushort);
  ushort* hbf = (ushort*)(ws + off); off += (size_t)Mrows * Dc * sizeof(ushort);
  float2* part = (float2*)(ws + off); off += (size_t)Mrows * NCHUNK * sizeof(float2);
  float* tgt = (float*)(ws + off); off += Mrows * sizeof(float);
  float* nll = (float*)(ws + off); off += Mrows * sizeof(float);
  (void)ws_size; (void)in_sizes; (void)n_in; (void)out_size;

  cast_f32_bf16<<<2048, 256, 0, stream>>>(weight, wbf, (size_t)Vc * Dc / 4);
  cast_f32_bf16<<<256, 256, 0, stream>>>(hidden, hbf, (size_t)Mrows * Dc / 4);
  tgt_kernel<<<Mrows / 4, 256, 0, stream>>>(hidden, weight, targets, tgt);

  gemm_lse2b<<<8000, 512, 0, stream>>>(hbf, wbf, part);  // mb=bid&15, nb=bid>>4

  lse_reduce<<<Mrows, 256, 0, stream>>>(part, tgt, targets, nll);
  final_kernel<<<1, 64, 0, stream>>>(nll, targets, out);
}

// Round 15
// 751.562 us; speedup vs baseline: 1.0524x; 1.0016x over previous
//
#include <hip/hip_runtime.h>
#include <hip/hip_bf16.h>
#include <math.h>

#define IGNORE_INDEX (-100)

static constexpr int Dc = 1024, Vc = 128000;
static constexpr int Mrows = 2048;        // B*S
static constexpr int Kdim = 1024;
static constexpr int BK = 32;
static constexpr int NT = Kdim / BK;      // 32 K-tiles
static constexpr int NCHUNK = Vc / 64;    // 2000 partial chunks per row

typedef __bf16 bf16x8_t __attribute__((ext_vector_type(8)));
typedef float f32x4_t __attribute__((ext_vector_type(4)));

__device__ __forceinline__ ushort f2bf(float f) {
  union { float f; unsigned u; } v; v.f = f;
  unsigned u = v.u;
  unsigned r = (u + 0x7FFFu + ((u >> 16) & 1u)) >> 16;  // round-nearest-even
  return (ushort)r;
}

// ---------------- cast fp32 -> bf16 (vectorized, grid-stride) ----------------
__global__ void cast_f32_bf16(const float* __restrict__ in, ushort* __restrict__ out,
                              size_t n4) {
  size_t i = (size_t)blockIdx.x * blockDim.x + threadIdx.x;
  size_t stride = (size_t)gridDim.x * blockDim.x;
  for (; i < n4; i += stride) {
    float4 v = reinterpret_cast<const float4*>(in)[i];
    ushort4 o;
    o.x = f2bf(v.x); o.y = f2bf(v.y); o.z = f2bf(v.z); o.w = f2bf(v.w);
    reinterpret_cast<ushort4*>(out)[i] = o;
  }
}

// ---------------- target logits: fp32 dot(hidden[r], weight[t[r]]) ----------------
__global__ void tgt_kernel(const float* __restrict__ hidden, const float* __restrict__ weight,
                           const int* __restrict__ targets, float* __restrict__ tgt) {
  int row = blockIdx.x * 4 + (threadIdx.x >> 6);
  int lane = threadIdx.x & 63;
  if (row >= Mrows) return;
  int t = targets[row];
  float sum = 0.f;
  if (t != IGNORE_INDEX) {
    const float* h = hidden + (size_t)row * Kdim;
    const float* wv = weight + (size_t)t * Kdim;
    for (int k = lane * 4; k < Kdim; k += 64 * 4) {
      float4 a = *reinterpret_cast<const float4*>(h + k);
      float4 b = *reinterpret_cast<const float4*>(wv + k);
      sum += a.x * b.x + a.y * b.y + a.z * b.z + a.w * b.w;
    }
  }
  #pragma unroll
  for (int d = 1; d < 64; d <<= 1) sum += __shfl_xor(sum, d);
  if (lane == 0) tgt[row] = sum;
}

// -- 128x256 8-wave 2-BLOCK/CU ring-3 GEMM (bf16 MFMA) + fused partial LSE ----
// R13 (verified): 2 blocks/CU via 64x64/wave (acc=64) + 48KB dbuf; occ 45.7%,
// MfmaUtil 40%, gemm 623us. Remaining stall: tile-end vmcnt(0) drain (T4).
// THIS ROUND: 3-deep ring (72KB, still 2 blocks/CU) + counted vmcnt(3):
// stage t+2 at tile top; at tile end wait vmcnt(3) -> t+1's loads retired,
// t+2's 3 ride across the barrier. SAFETY (R8 lesson refined): counts are
// wave-UNIFORM, every thread issues the same 3-load STAGE sequence in program
// order, vmcnt retires in-order => after vmcnt(3)+barrier the t+1 buffer is
// complete block-wide. Tail: vmcnt(0) at t=NT-2 (tile NT-1's loads must land).
// Swizzle (R10/R13-measured ZERO conflicts, 64B rows): 16B slot' = slot^((row>>1)&3),
// linear LDS dest + inverse-swizzled GLOBAL source + swizzled ds_read (rule #21).
#define MFMA_BF16(A, B, C) __builtin_amdgcn_mfma_f32_16x16x32_bf16((A), (B), (C), 0, 0, 0)
#define GLDS(g, l) __builtin_amdgcn_global_load_lds( \
    (const __attribute__((address_space(1))) void*)(g), \
    (__attribute__((address_space(3))) void*)(l), 16, 0, 0)

__global__ __launch_bounds__(512, 4) void gemm_lse2b(const ushort* __restrict__ Abf,
                                                     const ushort* __restrict__ Bbf,
                                                     float2* __restrict__ part) {
  __shared__ ushort lds[3][3 * 4096];  // [ring][A(128x32) | B(256x32)] = 72KB
  const int tid = threadIdx.x;
  const int wid = tid >> 6, lane = tid & 63;
  const int wr = wid >> 2, wc = wid & 3;        // 2M x 4N wave grid, wave = 64x64 out
  const int l15 = lane & 15, l16 = lane >> 4;
  const int bid = blockIdx.x;
  const int mb = bid & 15;             // 16 M-blocks share one B panel (cross-XCD)
  const int nb = bid >> 4;             // 0..499

  // staging: A chunk c=tid (r=c>>2 in 0..127); B chunks c=tid, tid+512 (r 0..255)
  const int sr = tid >> 2, sslot = tid & 3;
  const int sko = ((sslot ^ ((sr >> 1) & 3)) << 3);       // inverse-swizzled src k
  const int sr2 = (tid + 512) >> 2;
  const int sko2 = ((sslot ^ ((sr2 >> 1) & 3)) << 3);
  const ushort* gA = Abf + (size_t)(mb * 128) * Kdim;
  const ushort* gB = Bbf + (size_t)(nb * 256) * Kdim;
  const ushort* sgA = gA + (size_t)sr * Kdim + sko;
  const ushort* sgB0 = gB + (size_t)sr * Kdim + sko;
  const ushort* sgB1 = gB + (size_t)sr2 * Kdim + sko2;

  // read-side: row stride 64B; frag row bases are multiples of 16 ->
  // (row>>1)&3 = (l15>>1)&3; logical k-slot l16 lives at slot l16^((l15>>1)&3).
  const int koff = ((l16 ^ ((l15 >> 1) & 3)) << 4);       // bytes
  const int aBase = (wr * 64 + l15) * 64 + koff;          // + mi*1024
  const int bBase = (wc * 64 + l15) * 64 + koff;          // + ni*1024 (within B)

  f32x4_t acc[4][4];
  #pragma unroll
  for (int i = 0; i < 4; ++i)
    #pragma unroll
    for (int j = 0; j < 4; ++j)
      acc[i][j] = (f32x4_t){0.f, 0.f, 0.f, 0.f};

  #define STAGE(bufp, k0) do { \
    GLDS(sgA + (k0), bufp + tid * 8); \
    GLDS(sgB0 + (k0), bufp + 4096 + tid * 8); \
    GLDS(sgB1 + (k0), bufp + 4096 + 4096 + tid * 8); \
  } while (0)

  // prologue: tiles 0,1 staged; vmcnt(3) -> tile0 landed, tile1's 3 in flight
  STAGE(lds[0], 0);
  STAGE(lds[1], BK);
  asm volatile("s_waitcnt vmcnt(3)" ::: "memory");
  __builtin_amdgcn_s_barrier();

  int cur = 0;
  for (int t = 0; t < NT; ++t) {
    if (t + 2 < NT) {
      int stg = cur + 2; if (stg >= 3) stg -= 3;
      STAGE(lds[stg], (t + 2) * BK);
    }
    const char* Ar = (const char*)lds[cur];
    const char* Br = (const char*)lds[cur] + 8192;
    bf16x8_t a[4], b[4];
    #pragma unroll
    for (int mi = 0; mi < 4; ++mi)
      a[mi] = *reinterpret_cast<const bf16x8_t*>(Ar + aBase + mi * 1024);
    #pragma unroll
    for (int ni = 0; ni < 4; ++ni)
      b[ni] = *reinterpret_cast<const bf16x8_t*>(Br + bBase + ni * 1024);
    __builtin_amdgcn_s_setprio(1);
    #pragma unroll
    for (int mi = 0; mi < 4; ++mi)
      #pragma unroll
      for (int ni = 0; ni < 4; ++ni)
        acc[mi][ni] = MFMA_BF16(a[mi], b[ni], acc[mi][ni]);
    __builtin_amdgcn_s_setprio(0);
    if (t + 1 < NT) {
      if (t + 2 < NT) asm volatile("s_waitcnt vmcnt(3)" ::: "memory");
      else            asm volatile("s_waitcnt vmcnt(0)" ::: "memory");
      __builtin_amdgcn_s_barrier();
    }
    cur = cur + 1; if (cur >= 3) cur = 0;
  }
  #undef STAGE

  // fused partial-LSE epilogue. acc[mi][ni][j]: row = wr*64+mi*16+l16*4+j,
  // col = wc*64+ni*16+l15 (m89-verified C/D layout)
  const int chunk = nb * 4 + wc;
  #pragma unroll
  for (int mi = 0; mi < 4; ++mi) {
    #pragma unroll
    for (int j = 0; j < 4; ++j) {
      float v0 = acc[mi][0][j], v1 = acc[mi][1][j], v2 = acc[mi][2][j], v3 = acc[mi][3][j];
      float mloc = fmaxf(fmaxf(v0, v1), fmaxf(v2, v3));
      #pragma unroll
      for (int d = 1; d < 16; d <<= 1) mloc = fmaxf(mloc, __shfl_xor(mloc, d));
      float sloc = __expf(v0 - mloc) + __expf(v1 - mloc) +
                   __expf(v2 - mloc) + __expf(v3 - mloc);
      #pragma unroll
      for (int d = 1; d < 16; d <<= 1) sloc += __shfl_xor(sloc, d);
      if (l15 == 0) {
        int grow = mb * 128 + wr * 64 + mi * 16 + l16 * 4 + j;
        part[(size_t)grow * NCHUNK + chunk] = make_float2(mloc, sloc);
      }
    }
  }
}

// ---------------- per-row merge of partials -> nll[row] ----------------
__device__ __forceinline__ void merge_ms(float& m, float& s, float m2, float s2) {
  if (m2 > m) { s = s * __expf(m - m2) + s2; m = m2; }
  else        { s += s2 * __expf(m2 - m); }
}

__global__ void lse_reduce(const float2* __restrict__ part, const float* __restrict__ tgt,
                           const int* __restrict__ targets, float* __restrict__ nll) {
  int row = blockIdx.x;
  const float2* p = part + (size_t)row * NCHUNK;
  float m = -INFINITY, s = 0.f;
  for (int c = threadIdx.x; c < NCHUNK; c += blockDim.x) {
    float2 v = p[c];
    merge_ms(m, s, v.x, v.y);
  }
  #pragma unroll
  for (int d = 1; d < 64; d <<= 1) {
    float m2 = __shfl_xor(m, d), s2 = __shfl_xor(s, d);
    merge_ms(m, s, m2, s2);
  }
  __shared__ float sm[4], ss[4];
  int wid = threadIdx.x >> 6, lane = threadIdx.x & 63;
  if (lane == 0) { sm[wid] = m; ss[wid] = s; }
  __syncthreads();
  if (threadIdx.x == 0) {
    #pragma unroll
    for (int w2 = 1; w2 < 4; ++w2) merge_ms(m, s, sm[w2], ss[w2]);
    int t = targets[row];
    float out = 0.f;
    if (t != IGNORE_INDEX) out = m + logf(s) - tgt[row];
    nll[row] = out;
  }
}

// ---------------- final scalar: sum(nll)/count ----------------
__global__ void final_kernel(const float* __restrict__ nll, const int* __restrict__ targets,
                             float* __restrict__ out) {
  float sum = 0.f, cnt = 0.f;
  for (int i = threadIdx.x; i < Mrows; i += 64) {
    sum += nll[i];
    cnt += (targets[i] != IGNORE_INDEX) ? 1.f : 0.f;
  }
  #pragma unroll
  for (int d = 1; d < 64; d <<= 1) {
    sum += __shfl_xor(sum, d);
    cnt += __shfl_xor(cnt, d);
  }
  if (threadIdx.x == 0)
    out[0] = (cnt == 0.f) ? sum : sum / fmaxf(cnt, 1.f);
}

extern "C" void kernel_launch(void* const* d_in, const int* in_sizes, int n_in,
                              void* d_out, int out_size, void* d_ws, size_t ws_size,
                              hipStream_t stream) {
  const float* hidden = (const float*)d_in[0];   // [2,1024,1024] f32
  const float* weight = (const float*)d_in[1];   // [128000,1024] f32
  const int* targets  = (const int*)d_in[2];     // [2,1024] i32
  float* out = (float*)d_out;

  char* ws = (char*)d_ws;
  size_t off = 0;
  ushort* wbf = (ushort*)(ws + off); off += (size_t)Vc * Dc * sizeof(ushort);
  ushort* hbf = (ushort*)(ws + off); off += (size_t)Mrows * Dc * sizeof(ushort);
  float2* part = (float2*)(ws + off); off += (size_t)Mrows * NCHUNK * sizeof(float2);
  float* tgt = (float*)(ws + off); off += Mrows * sizeof(float);
  float* nll = (float*)(ws + off); off += Mrows * sizeof(float);
  (void)ws_size; (void)in_sizes; (void)n_in; (void)out_size;

  cast_f32_bf16<<<2048, 256, 0, stream>>>(weight, wbf, (size_t)Vc * Dc / 4);
  cast_f32_bf16<<<256, 256, 0, stream>>>(hidden, hbf, (size_t)Mrows * Dc / 4);
  tgt_kernel<<<Mrows / 4, 256, 0, stream>>>(hidden, weight, targets, tgt);

  gemm_lse2b<<<8000, 512, 0, stream>>>(hbf, wbf, part);  // mb=bid&15, nb=bid>>4

  lse_reduce<<<Mrows, 256, 0, stream>>>(part, tgt, targets, nll);
  final_kernel<<<1, 64, 0, stream>>>(nll, targets, out);
}